// Round 11
// baseline (145.765 us; speedup 1.0000x reference)
//
#include <hip/hip_runtime.h>

#define H_ 160
#define W_ 160
#define HW_ (H_ * W_)
#define NPIX (8 * HW_)   // 204800 pixels

// ============================================================================
// R21: amortize per-block staging (the largest remaining VALU chunk, ~30-40%,
// identical across all 1600 blocks) + drop provably-dead zero-fill.
// R20 post-mortem: LDS 28->23KB raised static residency cap but measured
// occupancy stayed 29% -> per-block serial work limits, not residency.
//  - zero-fill DROPPED: MFMA D-col n depends only on B-lane n's fragment;
//    garbage in lanes n>=18 pollutes only acc cols 18-31, never read
//    (n<18 transpose guard). Verified mapping: lane = j + 32*kg.
//  - BOTH weight buffers resident (wsho 18432B + wshd 18432B + offl 4752B
//    = 41616B -> 3 blocks/CU; occupancy 12 waves, R13/R20 showed <=5% sens.).
//    Grid 800, T=2 adjacent tiles/block of the same XCD image: stage ONCE,
//    staging insts/tile halved, barriers/tile 3->2, halo L1 reuse.
//  - (256,3): VGPR cap 168, no spill risk (R17 lesson).
// Tile body verbatim R20 (62us-proven): f16-packed offl, cvt_pk packs,
// fences, XCD swizzle, bf16 MFMA layouts, f32x2 combine, C-write.
// Layouts (verified m74/m101 + R9 pass): A[m=lane&31][k=(lane>>5)*8+j],
// B[n=lane&31][k=...], D: col n=lane&31, row=(reg&3)+8*(reg>>2)+4*(lane>>5).
// ============================================================================

typedef __attribute__((ext_vector_type(8)))  short  short8;   // 8 bf16
typedef __attribute__((ext_vector_type(4)))  float  f32x4;
typedef __attribute__((ext_vector_type(2)))  float  f32x2;
typedef __attribute__((ext_vector_type(16))) float  f32x16;
typedef __attribute__((ext_vector_type(4)))  unsigned u32x4;

__device__ __forceinline__ unsigned short bf16_rne(float f) {
    unsigned u = __float_as_uint(f);
    u += 0x7fffu + ((u >> 16) & 1u);
    return (unsigned short)(u >> 16);
}
// v_cvt_pk_bf16_f32: dst.lo=bf16(a), dst.hi=bf16(b); RNE (R18-verified).
__device__ __forceinline__ unsigned cvt_pk_bf16(float a, float b) {
    unsigned r;
    asm("v_cvt_pk_bf16_f32 %0, %1, %2" : "=v"(r) : "v"(a), "v"(b));
    return r;
}
__device__ __forceinline__ f32x2 up2(unsigned u) {
    f32x2 r;
    r.x = __uint_as_float(u << 16);
    r.y = __uint_as_float(u & 0xffff0000u);
    return r;
}
__device__ __forceinline__ unsigned short f16_bits(float f) {
    _Float16 h = (_Float16)f;                 // v_cvt_f16_f32 (RNE)
    return __builtin_bit_cast(unsigned short, h);
}
__device__ __forceinline__ float f16_val(unsigned short u) {
    return (float)__builtin_bit_cast(_Float16, u);   // v_cvt_f32_f16
}

// ---- x (B,32,H,W) fp32 -> xT (B,H,W,32) bf16; 16B stores (R18 verbatim) ----
__global__ __launch_bounds__(256) void nhwc_bf16(
    const float* __restrict__ x, unsigned short* __restrict__ xT)
{
    const int pix = blockIdx.x * 256 + threadIdx.x;
    const int p = pix % HW_;
    const int b = pix / HW_;
    const float* __restrict__ src = x + (size_t)b * 32 * HW_ + p;
    u32x4* __restrict__ dst = (u32x4*)(xT + (size_t)pix * 32);
    #pragma unroll
    for (int q = 0; q < 4; ++q) {
        u32x4 v;
        v.x = cvt_pk_bf16(src[(8 * q + 0) * HW_], src[(8 * q + 1) * HW_]);
        v.y = cvt_pk_bf16(src[(8 * q + 2) * HW_], src[(8 * q + 3) * HW_]);
        v.z = cvt_pk_bf16(src[(8 * q + 4) * HW_], src[(8 * q + 5) * HW_]);
        v.w = cvt_pk_bf16(src[(8 * q + 6) * HW_], src[(8 * q + 7) * HW_]);
        dst[q] = v;
    }
}

// scatter-destination for flat weight index f (f = j*288 + c*9 + tap)
__device__ __forceinline__ int wsh_slot(unsigned f) {
    const unsigned j   = f / 288u;
    const unsigned rem = f - j * 288u;
    const unsigned c   = rem / 9u;
    const unsigned tap = rem - c * 9u;
    const unsigned unit = (tap * 2u + (c >> 4)) * 64u + j + 32u * ((c >> 3) & 1u);
    return (int)(unit * 8u + (c & 7u));
}

// ---- fused: offset conv + bilinear sampling + dcn GEMM + ReLU --------------
__global__ __launch_bounds__(256, 3) void dcn_fused(
    const unsigned short* __restrict__ xT,   // (8,160,160,32) bf16
    const float* __restrict__ w_off,         // (18, 32, 3, 3) = 5184 floats
    const float* __restrict__ b_off,         // (18,)
    const float* __restrict__ w_dcn,         // (32, 32, 3, 3) = 9216 floats
    float* __restrict__ out)                 // (8, 32, 160, 160)
{
    __shared__ __align__(16) unsigned short wsho[9 * 2 * 64 * 8];  // 18,432 B
    __shared__ __align__(16) unsigned short wshd[9 * 2 * 64 * 8];  // 18,432 B
    // per-wave offset transpose, packed (dy,dx) f16 per tap: [9][33] u32/wave
    __shared__ unsigned offl[4 * 9 * 33];                          //  4,752 B
    const int tid = threadIdx.x;

    // ---- stage BOTH weight buffers once per block (no zero-fill: garbage
    //      in wsho lanes j>=18 only reaches unread acc cols 18-31) ----
    for (unsigned f = tid; f < 5184u; f += 256u)
        wsho[wsh_slot(f)] = bf16_rne(w_off[f]);
    for (unsigned f = tid; f < 9216u; f += 256u)
        wshd[wsh_slot(f)] = bf16_rne(w_dcn[f]);
    __syncthreads();

    const int wave = tid >> 6, lane = tid & 63;
    const int n = lane & 31;          // pixel (A-row m) == out channel (D-col)
    const int hh = lane >> 5;         // k-group

    #define PREP(t, s) do { \
        const unsigned dyx = ow32[(t) * 33 + n]; \
        const float dy = f16_val((unsigned short)(dyx & 0xffffu)); \
        const float dx = f16_val((unsigned short)(dyx >> 16)); \
        const float py = (float)(h - 1 + (t) / 3) + dy; \
        const float px = (float)(w - 1 + (t) % 3) + dx; \
        const float fy0 = floorf(py), fx0 = floorf(px); \
        const float wy1 = py - fy0, wx1 = px - fx0; \
        const float wy0 = 1.0f - wy1, wx0 = 1.0f - wx1; \
        const int y0 = (int)fy0, x0 = (int)fx0; \
        const bool vy0 = (y0 >= 0) && (y0 < H_); \
        const bool vy1 = (y0 + 1 >= 0) && (y0 + 1 < H_); \
        const bool vx0 = (x0 >= 0) && (x0 < W_); \
        const bool vx1 = (x0 + 1 >= 0) && (x0 + 1 < W_); \
        cw[s].x = (vy0 && vx0) ? wy0 * wx0 : 0.0f; \
        cw[s].y = (vy0 && vx1) ? wy0 * wx1 : 0.0f; \
        cw[s].z = (vy1 && vx0) ? wy1 * wx0 : 0.0f; \
        cw[s].w = (vy1 && vx1) ? wy1 * wx1 : 0.0f; \
        const int yc0 = min(max(y0, 0), H_ - 1), yc1 = min(max(y0 + 1, 0), H_ - 1); \
        const int xc0 = min(max(x0, 0), W_ - 1), xc1 = min(max(x0 + 1, 0), W_ - 1); \
        const unsigned short* pA = xb + (size_t)(yc0 * W_ + xc0) * 32; \
        const unsigned short* pB = xb + (size_t)(yc0 * W_ + xc1) * 32; \
        const unsigned short* pC = xb + (size_t)(yc1 * W_ + xc0) * 32; \
        const unsigned short* pD = xb + (size_t)(yc1 * W_ + xc1) * 32; \
        gA0[s] = *(const u32x4*)(pA);  gA1[s] = *(const u32x4*)(pA + 16); \
        gB0[s] = *(const u32x4*)(pB);  gB1[s] = *(const u32x4*)(pB + 16); \
        gC0[s] = *(const u32x4*)(pC);  gC1[s] = *(const u32x4*)(pC + 16); \
        gD0[s] = *(const u32x4*)(pD);  gD1[s] = *(const u32x4*)(pD + 16); \
    } while (0)

    // ---- T=2 adjacent tiles of the same XCD image per block ----
    #pragma unroll 1
    for (int rep = 0; rep < 2; ++rep) {
        // XCD-chunked pair swizzle: grid 800, XCD k owns image k; pair p
        // covers tiles 2p, 2p+1 of that image. Bijective over 1600 tiles.
        const int bid = (blockIdx.x & 7) * 200 + ((int)blockIdx.x >> 3) * 2 + rep;
        const int pixbase = bid * 128 + wave * 32;
        const int pix = pixbase + n;
        const int w = pix % W_, h = (pix / W_) % H_, b = pix / HW_;
        const unsigned short* __restrict__ xb = xT + (size_t)b * HW_ * 32 + hh * 8;

        // ---- stage 1: offset conv GEMM, all 18 gathers issued up front ----
        {
            f32x16 acc = {};
            const u32x4 z4 = {0u, 0u, 0u, 0u};
            u32x4 lr[18];      // raw gathers (static indices under full unroll)
            int   va[9];       // per-tap validity
            #pragma unroll
            for (int tap = 0; tap < 9; ++tap) {
                const int yy = h - 1 + tap / 3;
                const int xx = w - 1 + tap % 3;
                va[tap] = (yy >= 0) && (yy < H_) && (xx >= 0) && (xx < W_);
                const int idx = min(max(yy, 0), H_ - 1) * W_ + min(max(xx, 0), W_ - 1);
                const unsigned short* __restrict__ px_ = xb + (size_t)idx * 32;
                lr[2 * tap]     = *(const u32x4*)(px_);
                lr[2 * tap + 1] = *(const u32x4*)(px_ + 16);
            }
            __builtin_amdgcn_sched_barrier(0);   // all 18 loads issue first
            #pragma unroll
            for (int tap = 0; tap < 9; ++tap) {
                const u32x4 l0 = va[tap] ? lr[2 * tap]     : z4;
                const u32x4 l1 = va[tap] ? lr[2 * tap + 1] : z4;
                const short8 a0 = __builtin_bit_cast(short8, l0);
                const short8 a1 = __builtin_bit_cast(short8, l1);
                const short8 b0 = *(const short8*)(wsho + ((tap * 2 + 0) * 64 + lane) * 8);
                const short8 b1 = *(const short8*)(wsho + ((tap * 2 + 1) * 64 + lane) * 8);
                acc = __builtin_amdgcn_mfma_f32_32x32x16_bf16(a0, b0, acc, 0, 0, 0);
                acc = __builtin_amdgcn_mfma_f32_32x32x16_bf16(a1, b1, acc, 0, 0, 0);
            }
            // D-layout -> per-wave LDS transpose, f16-packed:
            // word [j>>1][prow], half (j&1): lo=dy (j even), hi=dx (j odd)
            if (n < 18) {
                const float bia = b_off[n];
                unsigned short* __restrict__ owp =
                    (unsigned short*)(offl + wave * 297) + (n >> 1) * 66 + (n & 1);
                #pragma unroll
                for (int r = 0; r < 16; ++r) {
                    const int prow = (r & 3) + 8 * (r >> 2) + 4 * hh;
                    owp[prow * 2] = f16_bits(acc[r] + bia);
                }
            }
        }
        __syncthreads();   // offl visible (cross-lane within wave via LDS)

        // ---- stage 2: bilinear sampling + dcn GEMM, depth-1 pipelined -----
        const unsigned* __restrict__ ow32 = offl + wave * 297;
        f32x16 acc = {};

        u32x4 gA0[2], gA1[2], gB0[2], gB1[2], gC0[2], gC1[2], gD0[2], gD1[2];
        f32x4 cw[2];   // {w00, w01, w10, w11}

        PREP(0, 0);
        #pragma unroll
        for (int tap = 0; tap < 9; ++tap) {
            const int cur = tap & 1, nxt = cur ^ 1;
            if (tap < 8) PREP(tap + 1, nxt);   // issue next tap's 8 gathers
            __builtin_amdgcn_sched_barrier(0); // pin: loads stay above combine

            const float w00 = cw[cur].x, w01 = cw[cur].y;
            const float w10 = cw[cur].z, w11 = cw[cur].w;
            // packed-fp32 bilinear combine + 1-op RNE bf16 pack
            #define COMB(a, bb, cc, dd) ({ \
                const f32x2 v = up2(a) * w00 + up2(bb) * w01 + up2(cc) * w10 + up2(dd) * w11; \
                cvt_pk_bf16(v.x, v.y); })
            u32x4 av0, av1;
            av0.x = COMB(gA0[cur].x, gB0[cur].x, gC0[cur].x, gD0[cur].x);
            av0.y = COMB(gA0[cur].y, gB0[cur].y, gC0[cur].y, gD0[cur].y);
            av0.z = COMB(gA0[cur].z, gB0[cur].z, gC0[cur].z, gD0[cur].z);
            av0.w = COMB(gA0[cur].w, gB0[cur].w, gC0[cur].w, gD0[cur].w);
            av1.x = COMB(gA1[cur].x, gB1[cur].x, gC1[cur].x, gD1[cur].x);
            av1.y = COMB(gA1[cur].y, gB1[cur].y, gC1[cur].y, gD1[cur].y);
            av1.z = COMB(gA1[cur].z, gB1[cur].z, gC1[cur].z, gD1[cur].z);
            av1.w = COMB(gA1[cur].w, gB1[cur].w, gC1[cur].w, gD1[cur].w);
            #undef COMB

            const short8 a0 = __builtin_bit_cast(short8, av0);
            const short8 a1 = __builtin_bit_cast(short8, av1);
            const short8 b0 = *(const short8*)(wshd + ((tap * 2 + 0) * 64 + lane) * 8);
            const short8 b1 = *(const short8*)(wshd + ((tap * 2 + 1) * 64 + lane) * 8);
            acc = __builtin_amdgcn_mfma_f32_32x32x16_bf16(a0, b0, acc, 0, 0, 0);
            acc = __builtin_amdgcn_mfma_f32_32x32x16_bf16(a1, b1, acc, 0, 0, 0);
        }

        // D: col o = n; rows = pixels pixbase + g*8 + 4*hh + i
        float* __restrict__ ob = out + (size_t)b * 32 * HW_ + (size_t)n * HW_
                               + (pixbase - b * HW_) + 4 * hh;
        #pragma unroll
        for (int g = 0; g < 4; ++g) {
            f32x4 r;
            #pragma unroll
            for (int i = 0; i < 4; ++i) r[i] = fmaxf(acc[g * 4 + i], 0.0f);
            *(f32x4*)(ob + g * 8) = r;
        }

        if (rep == 0) __syncthreads();   // offl reuse hazard across tiles
    }
    #undef PREP
}

extern "C" void kernel_launch(void* const* d_in, const int* in_sizes, int n_in,
                              void* d_out, int out_size, void* d_ws, size_t ws_size,
                              hipStream_t stream) {
    const float* x     = (const float*)d_in[0];
    const float* w_off = (const float*)d_in[1];
    const float* b_off = (const float*)d_in[2];
    const float* w_dcn = (const float*)d_in[3];
    float* out = (float*)d_out;

    unsigned short* xT = (unsigned short*)d_ws;   // 13.1 MB bf16 NHWC (R11 footprint)

    nhwc_bf16<<<800, 256, 0, stream>>>(x, xT);
    dcn_fused<<<800, 256, 0, stream>>>(xT, w_off, b_off, w_dcn, out);
}

// Round 13
// 144.588 us; speedup vs baseline: 1.0081x; 1.0081x over previous
//
#include <hip/hip_runtime.h>

#define H_ 160
#define W_ 160
#define HW_ (H_ * W_)
#define NPIX (8 * HW_)   // 204800 pixels

// ============================================================================
// R23: R20 base (63us proven) + the two VALIDATED cuts from the R21/R22 pair.
// R22 isolation: pk_mul/pk_fma inline asm = numeric poison (absmax 2.63) ->
// permanently dead. zero-fill drop = validated (R21 passed with it).
//  - zero-fill DROPPED: wsh garbage lanes j>=18 reach only MFMA D-cols 18-31,
//    never read past the n<18 transpose guard (R21-proven).
//  - pair-staging: weights loaded as float2 (loads 56->28/thread), converted
//    with ONE v_cvt_pk_bf16_f32 per pair (R18-proven RNE-identical);
//    ds_write_b16 stores the low half free, 1 lshrrev for the high.
//    Same values, same slot mapping, same final LDS contents.
// Everything else verbatim R20: (256,4), single time-shared wsh, f16-packed
// offl, fences, XCD swizzle, scalar-f32x2 combine (PROVEN numerics), C-write.
// Layouts (verified m74/m101 + R9 pass): A[m=lane&31][k=(lane>>5)*8+j],
// B[n=lane&31][k=...], D: col n=lane&31, row=(reg&3)+8*(reg>>2)+4*(lane>>5).
// ============================================================================

typedef __attribute__((ext_vector_type(8)))  short  short8;   // 8 bf16
typedef __attribute__((ext_vector_type(4)))  float  f32x4;
typedef __attribute__((ext_vector_type(2)))  float  f32x2;
typedef __attribute__((ext_vector_type(16))) float  f32x16;
typedef __attribute__((ext_vector_type(4)))  unsigned u32x4;

// v_cvt_pk_bf16_f32: dst.lo=bf16(a), dst.hi=bf16(b); RNE (R18-verified).
__device__ __forceinline__ unsigned cvt_pk_bf16(float a, float b) {
    unsigned r;
    asm("v_cvt_pk_bf16_f32 %0, %1, %2" : "=v"(r) : "v"(a), "v"(b));
    return r;
}
__device__ __forceinline__ f32x2 up2(unsigned u) {
    f32x2 r;
    r.x = __uint_as_float(u << 16);
    r.y = __uint_as_float(u & 0xffff0000u);
    return r;
}
__device__ __forceinline__ unsigned short f16_bits(float f) {
    _Float16 h = (_Float16)f;                 // v_cvt_f16_f32 (RNE)
    return __builtin_bit_cast(unsigned short, h);
}
__device__ __forceinline__ float f16_val(unsigned short u) {
    return (float)__builtin_bit_cast(_Float16, u);   // v_cvt_f32_f16
}

// ---- x (B,32,H,W) fp32 -> xT (B,H,W,32) bf16; 16B stores (R18 verbatim) ----
__global__ __launch_bounds__(256) void nhwc_bf16(
    const float* __restrict__ x, unsigned short* __restrict__ xT)
{
    const int pix = blockIdx.x * 256 + threadIdx.x;
    const int p = pix % HW_;
    const int b = pix / HW_;
    const float* __restrict__ src = x + (size_t)b * 32 * HW_ + p;
    u32x4* __restrict__ dst = (u32x4*)(xT + (size_t)pix * 32);
    #pragma unroll
    for (int q = 0; q < 4; ++q) {
        u32x4 v;
        v.x = cvt_pk_bf16(src[(8 * q + 0) * HW_], src[(8 * q + 1) * HW_]);
        v.y = cvt_pk_bf16(src[(8 * q + 2) * HW_], src[(8 * q + 3) * HW_]);
        v.z = cvt_pk_bf16(src[(8 * q + 4) * HW_], src[(8 * q + 5) * HW_]);
        v.w = cvt_pk_bf16(src[(8 * q + 6) * HW_], src[(8 * q + 7) * HW_]);
        dst[q] = v;
    }
}

// scatter-destination for flat weight index f (f = j*288 + c*9 + tap)
__device__ __forceinline__ int wsh_slot(unsigned f) {
    const unsigned j   = f / 288u;
    const unsigned rem = f - j * 288u;
    const unsigned c   = rem / 9u;
    const unsigned tap = rem - c * 9u;
    const unsigned unit = (tap * 2u + (c >> 4)) * 64u + j + 32u * ((c >> 3) & 1u);
    return (int)(unit * 8u + (c & 7u));
}

// ---- fused: offset conv + bilinear sampling + dcn GEMM + ReLU --------------
__global__ __launch_bounds__(256, 4) void dcn_fused(
    const unsigned short* __restrict__ xT,   // (8,160,160,32) bf16
    const float* __restrict__ w_off,         // (18, 32, 3, 3) = 5184 floats
    const float* __restrict__ b_off,         // (18,)
    const float* __restrict__ w_dcn,         // (32, 32, 3, 3) = 9216 floats
    float* __restrict__ out)                 // (8, 32, 160, 160)
{
    // ONE weight-frag buffer, time-shared: wo in stage 1, wd in stage 2.
    // NO zero-fill: garbage in lanes j>=18 only reaches unread acc cols 18-31.
    __shared__ __align__(16) unsigned short wsh[9 * 2 * 64 * 8];  // 18,432 B
    // per-wave offset transpose, packed (dy,dx) f16 per tap: [9][33] u32/wave
    __shared__ unsigned offl[4 * 9 * 33];                         //  4,752 B
    const int tid = threadIdx.x;

    // ---- stage wo: float2 pair loads + cvt_pk + scatter (2592 pairs) ----
    for (unsigned p = tid; p < 2592u; p += 256u) {
        const unsigned f = 2u * p;
        const f32x2 v = *((const f32x2*)w_off + p);
        const unsigned pk = cvt_pk_bf16(v.x, v.y);
        wsh[wsh_slot(f)]      = (unsigned short)pk;          // ds_write_b16 lo
        wsh[wsh_slot(f + 1u)] = (unsigned short)(pk >> 16);  // hi
    }
    __syncthreads();

    const int wave = tid >> 6, lane = tid & 63;
    const int n = lane & 31;          // pixel (A-row m) == out channel (D-col)
    const int hh = lane >> 5;         // k-group
    // XCD-chunked swizzle: XCD k owns batch k (200 blocks = one image = 1.6MB
    // xT -> L2-resident per XCD). Bijective since 1600 % 8 == 0.
    const int bid = (blockIdx.x & 7) * 200 + (blockIdx.x >> 3);
    const int pixbase = bid * 128 + wave * 32;
    const int pix = pixbase + n;
    const int w = pix % W_, h = (pix / W_) % H_, b = pix / HW_;
    const unsigned short* __restrict__ xb = xT + (size_t)b * HW_ * 32 + hh * 8;

    // ------- stage 1: offset conv GEMM, all 18 gathers issued up front -----
    {
        f32x16 acc = {};
        const u32x4 z4 = {0u, 0u, 0u, 0u};
        u32x4 lr[18];      // raw gathers (static indices under full unroll)
        int   va[9];       // per-tap validity
        #pragma unroll
        for (int tap = 0; tap < 9; ++tap) {
            const int yy = h - 1 + tap / 3;
            const int xx = w - 1 + tap % 3;
            va[tap] = (yy >= 0) && (yy < H_) && (xx >= 0) && (xx < W_);
            const int idx = min(max(yy, 0), H_ - 1) * W_ + min(max(xx, 0), W_ - 1);
            const unsigned short* __restrict__ px_ = xb + (size_t)idx * 32;
            lr[2 * tap]     = *(const u32x4*)(px_);
            lr[2 * tap + 1] = *(const u32x4*)(px_ + 16);
        }
        __builtin_amdgcn_sched_barrier(0);   // all 18 loads issue before use
        #pragma unroll
        for (int tap = 0; tap < 9; ++tap) {
            const u32x4 l0 = va[tap] ? lr[2 * tap]     : z4;
            const u32x4 l1 = va[tap] ? lr[2 * tap + 1] : z4;
            const short8 a0 = __builtin_bit_cast(short8, l0);
            const short8 a1 = __builtin_bit_cast(short8, l1);
            const short8 b0 = *(const short8*)(wsh + ((tap * 2 + 0) * 64 + lane) * 8);
            const short8 b1 = *(const short8*)(wsh + ((tap * 2 + 1) * 64 + lane) * 8);
            acc = __builtin_amdgcn_mfma_f32_32x32x16_bf16(a0, b0, acc, 0, 0, 0);
            acc = __builtin_amdgcn_mfma_f32_32x32x16_bf16(a1, b1, acc, 0, 0, 0);
        }
        // D-layout -> per-wave LDS transpose, f16-packed:
        // word [j>>1][prow], half (j&1): lo=dy (j even), hi=dx (j odd)
        if (n < 18) {
            const float bia = b_off[n];
            unsigned short* __restrict__ owp =
                (unsigned short*)(offl + wave * 297) + (n >> 1) * 66 + (n & 1);
            #pragma unroll
            for (int r = 0; r < 16; ++r) {
                const int prow = (r & 3) + 8 * (r >> 2) + 4 * hh;
                owp[prow * 2] = f16_bits(acc[r] + bia);
            }
        }
    }
    __syncthreads();   // stage-1 reads of wsh done everywhere; offl visible

    // ---- re-stage wd: float2 pair loads + cvt_pk + scatter (4608 pairs) ----
    for (unsigned p = tid; p < 4608u; p += 256u) {
        const unsigned f = 2u * p;
        const f32x2 v = *((const f32x2*)w_dcn + p);
        const unsigned pk = cvt_pk_bf16(v.x, v.y);
        wsh[wsh_slot(f)]      = (unsigned short)pk;
        wsh[wsh_slot(f + 1u)] = (unsigned short)(pk >> 16);
    }
    __syncthreads();   // wd visible

    // ------ stage 2: bilinear sampling + dcn GEMM, depth-1 pipelined -------
    const unsigned* __restrict__ ow32 = offl + wave * 297;
    f32x16 acc = {};

    // double-buffered pipeline state (indices static under full unroll)
    u32x4 gA0[2], gA1[2], gB0[2], gB1[2], gC0[2], gC1[2], gD0[2], gD1[2];
    f32x4 cw[2];   // {w00, w01, w10, w11}

    #define PREP(t, s) do { \
        const unsigned dyx = ow32[(t) * 33 + n]; \
        const float dy = f16_val((unsigned short)(dyx & 0xffffu)); \
        const float dx = f16_val((unsigned short)(dyx >> 16)); \
        const float py = (float)(h - 1 + (t) / 3) + dy; \
        const float px = (float)(w - 1 + (t) % 3) + dx; \
        const float fy0 = floorf(py), fx0 = floorf(px); \
        const float wy1 = py - fy0, wx1 = px - fx0; \
        const float wy0 = 1.0f - wy1, wx0 = 1.0f - wx1; \
        const int y0 = (int)fy0, x0 = (int)fx0; \
        const bool vy0 = (y0 >= 0) && (y0 < H_); \
        const bool vy1 = (y0 + 1 >= 0) && (y0 + 1 < H_); \
        const bool vx0 = (x0 >= 0) && (x0 < W_); \
        const bool vx1 = (x0 + 1 >= 0) && (x0 + 1 < W_); \
        cw[s].x = (vy0 && vx0) ? wy0 * wx0 : 0.0f; \
        cw[s].y = (vy0 && vx1) ? wy0 * wx1 : 0.0f; \
        cw[s].z = (vy1 && vx0) ? wy1 * wx0 : 0.0f; \
        cw[s].w = (vy1 && vx1) ? wy1 * wx1 : 0.0f; \
        const int yc0 = min(max(y0, 0), H_ - 1), yc1 = min(max(y0 + 1, 0), H_ - 1); \
        const int xc0 = min(max(x0, 0), W_ - 1), xc1 = min(max(x0 + 1, 0), W_ - 1); \
        const unsigned short* pA = xb + (size_t)(yc0 * W_ + xc0) * 32; \
        const unsigned short* pB = xb + (size_t)(yc0 * W_ + xc1) * 32; \
        const unsigned short* pC = xb + (size_t)(yc1 * W_ + xc0) * 32; \
        const unsigned short* pD = xb + (size_t)(yc1 * W_ + xc1) * 32; \
        gA0[s] = *(const u32x4*)(pA);  gA1[s] = *(const u32x4*)(pA + 16); \
        gB0[s] = *(const u32x4*)(pB);  gB1[s] = *(const u32x4*)(pB + 16); \
        gC0[s] = *(const u32x4*)(pC);  gC1[s] = *(const u32x4*)(pC + 16); \
        gD0[s] = *(const u32x4*)(pD);  gD1[s] = *(const u32x4*)(pD + 16); \
    } while (0)

    PREP(0, 0);
    #pragma unroll
    for (int tap = 0; tap < 9; ++tap) {
        const int cur = tap & 1, nxt = cur ^ 1;
        if (tap < 8) PREP(tap + 1, nxt);   // issue next tap's 8 gathers
        __builtin_amdgcn_sched_barrier(0); // pin: loads stay above combine

        const float w00 = cw[cur].x, w01 = cw[cur].y;
        const float w10 = cw[cur].z, w11 = cw[cur].w;
        // PROVEN scalar-f32x2 bilinear combine + 1-op RNE bf16 pack
        #define COMB(a, bb, cc, dd) ({ \
            const f32x2 v = up2(a) * w00 + up2(bb) * w01 + up2(cc) * w10 + up2(dd) * w11; \
            cvt_pk_bf16(v.x, v.y); })
        u32x4 av0, av1;
        av0.x = COMB(gA0[cur].x, gB0[cur].x, gC0[cur].x, gD0[cur].x);
        av0.y = COMB(gA0[cur].y, gB0[cur].y, gC0[cur].y, gD0[cur].y);
        av0.z = COMB(gA0[cur].z, gB0[cur].z, gC0[cur].z, gD0[cur].z);
        av0.w = COMB(gA0[cur].w, gB0[cur].w, gC0[cur].w, gD0[cur].w);
        av1.x = COMB(gA1[cur].x, gB1[cur].x, gC1[cur].x, gD1[cur].x);
        av1.y = COMB(gA1[cur].y, gB1[cur].y, gC1[cur].y, gD1[cur].y);
        av1.z = COMB(gA1[cur].z, gB1[cur].z, gC1[cur].z, gD1[cur].z);
        av1.w = COMB(gA1[cur].w, gB1[cur].w, gC1[cur].w, gD1[cur].w);
        #undef COMB

        const short8 a0 = __builtin_bit_cast(short8, av0);
        const short8 a1 = __builtin_bit_cast(short8, av1);
        const short8 b0 = *(const short8*)(wsh + ((tap * 2 + 0) * 64 + lane) * 8);
        const short8 b1 = *(const short8*)(wsh + ((tap * 2 + 1) * 64 + lane) * 8);
        acc = __builtin_amdgcn_mfma_f32_32x32x16_bf16(a0, b0, acc, 0, 0, 0);
        acc = __builtin_amdgcn_mfma_f32_32x32x16_bf16(a1, b1, acc, 0, 0, 0);
    }
    #undef PREP

    // D: col o = n; rows = pixels pixbase + g*8 + 4*hh + i
    float* __restrict__ ob = out + (size_t)b * 32 * HW_ + (size_t)n * HW_
                           + (pixbase - b * HW_) + 4 * hh;
    #pragma unroll
    for (int g = 0; g < 4; ++g) {
        f32x4 r;
        #pragma unroll
        for (int i = 0; i < 4; ++i) r[i] = fmaxf(acc[g * 4 + i], 0.0f);
        *(f32x4*)(ob + g * 8) = r;
    }
}

extern "C" void kernel_launch(void* const* d_in, const int* in_sizes, int n_in,
                              void* d_out, int out_size, void* d_ws, size_t ws_size,
                              hipStream_t stream) {
    const float* x     = (const float*)d_in[0];
    const float* w_off = (const float*)d_in[1];
    const float* b_off = (const float*)d_in[2];
    const float* w_dcn = (const float*)d_in[3];
    float* out = (float*)d_out;

    unsigned short* xT = (unsigned short*)d_ws;   // 13.1 MB bf16 NHWC (R11 footprint)

    nhwc_bf16<<<800, 256, 0, stream>>>(x, xT);
    dcn_fused<<<1600, 256, 0, stream>>>(xT, w_off, b_off, w_dcn, out);
}

// Round 14
// 138.601 us; speedup vs baseline: 1.0517x; 1.0432x over previous
//
#include <hip/hip_runtime.h>

#define H_ 160
#define W_ 160
#define HW_ (H_ * W_)
#define NPIX (8 * HW_)   // 204800 pixels

// ============================================================================
// R24: R20 verbatim (proven 62-63us dcn, best-family config) MINUS the
// 4032-slot zero-fill (R21/R23-validated safe: wsh garbage in lanes j>=18
// reaches only MFMA D-cols 18-31, never read past the n<18 transpose guard).
// R23 post-mortem: pair-staging (load->cvt_pk->2 scatter writes w/ 2 slot
// divides) regressed ~5us OR session noise -> dropped, back to independent
// scalar staging loads (R20's form). Single variable vs R20 = work removal.
// Config: (256,4), single time-shared wsh (18432B), f16-packed offl (4752B),
// LDS 23552 -> 5-6 blocks/CU; XCD-chunked swizzle; depth-1 stage-2 pipeline
// with sched fences; cvt_pk bf16 packs (RNE); f32x2 scalar combine (PROVEN).
// Layouts (verified m74/m101 + R9 pass): A[m=lane&31][k=(lane>>5)*8+j],
// B[n=lane&31][k=...], D: col n=lane&31, row=(reg&3)+8*(reg>>2)+4*(lane>>5).
// ============================================================================

typedef __attribute__((ext_vector_type(8)))  short  short8;   // 8 bf16
typedef __attribute__((ext_vector_type(4)))  float  f32x4;
typedef __attribute__((ext_vector_type(2)))  float  f32x2;
typedef __attribute__((ext_vector_type(16))) float  f32x16;
typedef __attribute__((ext_vector_type(4)))  unsigned u32x4;

__device__ __forceinline__ unsigned short bf16_rne(float f) {
    unsigned u = __float_as_uint(f);
    u += 0x7fffu + ((u >> 16) & 1u);
    return (unsigned short)(u >> 16);
}
// v_cvt_pk_bf16_f32: dst.lo=bf16(a), dst.hi=bf16(b); RNE (R18-verified).
__device__ __forceinline__ unsigned cvt_pk_bf16(float a, float b) {
    unsigned r;
    asm("v_cvt_pk_bf16_f32 %0, %1, %2" : "=v"(r) : "v"(a), "v"(b));
    return r;
}
__device__ __forceinline__ f32x2 up2(unsigned u) {
    f32x2 r;
    r.x = __uint_as_float(u << 16);
    r.y = __uint_as_float(u & 0xffff0000u);
    return r;
}
__device__ __forceinline__ unsigned short f16_bits(float f) {
    _Float16 h = (_Float16)f;                 // v_cvt_f16_f32 (RNE)
    return __builtin_bit_cast(unsigned short, h);
}
__device__ __forceinline__ float f16_val(unsigned short u) {
    return (float)__builtin_bit_cast(_Float16, u);   // v_cvt_f32_f16
}

// ---- x (B,32,H,W) fp32 -> xT (B,H,W,32) bf16; 16B stores (R18 verbatim) ----
__global__ __launch_bounds__(256) void nhwc_bf16(
    const float* __restrict__ x, unsigned short* __restrict__ xT)
{
    const int pix = blockIdx.x * 256 + threadIdx.x;
    const int p = pix % HW_;
    const int b = pix / HW_;
    const float* __restrict__ src = x + (size_t)b * 32 * HW_ + p;
    u32x4* __restrict__ dst = (u32x4*)(xT + (size_t)pix * 32);
    #pragma unroll
    for (int q = 0; q < 4; ++q) {
        u32x4 v;
        v.x = cvt_pk_bf16(src[(8 * q + 0) * HW_], src[(8 * q + 1) * HW_]);
        v.y = cvt_pk_bf16(src[(8 * q + 2) * HW_], src[(8 * q + 3) * HW_]);
        v.z = cvt_pk_bf16(src[(8 * q + 4) * HW_], src[(8 * q + 5) * HW_]);
        v.w = cvt_pk_bf16(src[(8 * q + 6) * HW_], src[(8 * q + 7) * HW_]);
        dst[q] = v;
    }
}

// scatter-destination for flat weight index f (f = j*288 + c*9 + tap)
__device__ __forceinline__ int wsh_slot(unsigned f) {
    const unsigned j   = f / 288u;
    const unsigned rem = f - j * 288u;
    const unsigned c   = rem / 9u;
    const unsigned tap = rem - c * 9u;
    const unsigned unit = (tap * 2u + (c >> 4)) * 64u + j + 32u * ((c >> 3) & 1u);
    return (int)(unit * 8u + (c & 7u));
}

// ---- fused: offset conv + bilinear sampling + dcn GEMM + ReLU --------------
__global__ __launch_bounds__(256, 4) void dcn_fused(
    const unsigned short* __restrict__ xT,   // (8,160,160,32) bf16
    const float* __restrict__ w_off,         // (18, 32, 3, 3) = 5184 floats
    const float* __restrict__ b_off,         // (18,)
    const float* __restrict__ w_dcn,         // (32, 32, 3, 3) = 9216 floats
    float* __restrict__ out)                 // (8, 32, 160, 160)
{
    // ONE weight-frag buffer, time-shared: wo in stage 1, wd in stage 2.
    // NO zero-fill: garbage in lanes j>=18 only reaches unread acc cols 18-31.
    __shared__ __align__(16) unsigned short wsh[9 * 2 * 64 * 8];  // 18,432 B
    // per-wave offset transpose, packed (dy,dx) f16 per tap: [9][33] u32/wave
    __shared__ unsigned offl[4 * 9 * 33];                         //  4,752 B
    const int tid = threadIdx.x;

    // ---- stage wo: flat-coalesced loads + scatter (5184 floats) ----
    for (unsigned f = tid; f < 5184u; f += 256u)
        wsh[wsh_slot(f)] = bf16_rne(w_off[f]);
    __syncthreads();

    const int wave = tid >> 6, lane = tid & 63;
    const int n = lane & 31;          // pixel (A-row m) == out channel (D-col)
    const int hh = lane >> 5;         // k-group
    // XCD-chunked swizzle: XCD k owns batch k (200 blocks = one image = 1.6MB
    // xT -> L2-resident per XCD). Bijective since 1600 % 8 == 0.
    const int bid = (blockIdx.x & 7) * 200 + (blockIdx.x >> 3);
    const int pixbase = bid * 128 + wave * 32;
    const int pix = pixbase + n;
    const int w = pix % W_, h = (pix / W_) % H_, b = pix / HW_;
    const unsigned short* __restrict__ xb = xT + (size_t)b * HW_ * 32 + hh * 8;

    // ------- stage 1: offset conv GEMM, all 18 gathers issued up front -----
    {
        f32x16 acc = {};
        const u32x4 z4 = {0u, 0u, 0u, 0u};
        u32x4 lr[18];      // raw gathers (static indices under full unroll)
        int   va[9];       // per-tap validity
        #pragma unroll
        for (int tap = 0; tap < 9; ++tap) {
            const int yy = h - 1 + tap / 3;
            const int xx = w - 1 + tap % 3;
            va[tap] = (yy >= 0) && (yy < H_) && (xx >= 0) && (xx < W_);
            const int idx = min(max(yy, 0), H_ - 1) * W_ + min(max(xx, 0), W_ - 1);
            const unsigned short* __restrict__ px_ = xb + (size_t)idx * 32;
            lr[2 * tap]     = *(const u32x4*)(px_);
            lr[2 * tap + 1] = *(const u32x4*)(px_ + 16);
        }
        __builtin_amdgcn_sched_barrier(0);   // all 18 loads issue before use
        #pragma unroll
        for (int tap = 0; tap < 9; ++tap) {
            const u32x4 l0 = va[tap] ? lr[2 * tap]     : z4;
            const u32x4 l1 = va[tap] ? lr[2 * tap + 1] : z4;
            const short8 a0 = __builtin_bit_cast(short8, l0);
            const short8 a1 = __builtin_bit_cast(short8, l1);
            const short8 b0 = *(const short8*)(wsh + ((tap * 2 + 0) * 64 + lane) * 8);
            const short8 b1 = *(const short8*)(wsh + ((tap * 2 + 1) * 64 + lane) * 8);
            acc = __builtin_amdgcn_mfma_f32_32x32x16_bf16(a0, b0, acc, 0, 0, 0);
            acc = __builtin_amdgcn_mfma_f32_32x32x16_bf16(a1, b1, acc, 0, 0, 0);
        }
        // D-layout -> per-wave LDS transpose, f16-packed:
        // word [j>>1][prow], half (j&1): lo=dy (j even), hi=dx (j odd)
        if (n < 18) {
            const float bia = b_off[n];
            unsigned short* __restrict__ owp =
                (unsigned short*)(offl + wave * 297) + (n >> 1) * 66 + (n & 1);
            #pragma unroll
            for (int r = 0; r < 16; ++r) {
                const int prow = (r & 3) + 8 * (r >> 2) + 4 * hh;
                owp[prow * 2] = f16_bits(acc[r] + bia);
            }
        }
    }
    __syncthreads();   // stage-1 reads of wsh done everywhere; offl visible

    // ---- re-stage wd: flat-coalesced loads + scatter (9216 floats) ----
    for (unsigned f = tid; f < 9216u; f += 256u)
        wsh[wsh_slot(f)] = bf16_rne(w_dcn[f]);
    __syncthreads();   // wd visible

    // ------ stage 2: bilinear sampling + dcn GEMM, depth-1 pipelined -------
    const unsigned* __restrict__ ow32 = offl + wave * 297;
    f32x16 acc = {};

    // double-buffered pipeline state (indices static under full unroll)
    u32x4 gA0[2], gA1[2], gB0[2], gB1[2], gC0[2], gC1[2], gD0[2], gD1[2];
    f32x4 cw[2];   // {w00, w01, w10, w11}

    #define PREP(t, s) do { \
        const unsigned dyx = ow32[(t) * 33 + n]; \
        const float dy = f16_val((unsigned short)(dyx & 0xffffu)); \
        const float dx = f16_val((unsigned short)(dyx >> 16)); \
        const float py = (float)(h - 1 + (t) / 3) + dy; \
        const float px = (float)(w - 1 + (t) % 3) + dx; \
        const float fy0 = floorf(py), fx0 = floorf(px); \
        const float wy1 = py - fy0, wx1 = px - fx0; \
        const float wy0 = 1.0f - wy1, wx0 = 1.0f - wx1; \
        const int y0 = (int)fy0, x0 = (int)fx0; \
        const bool vy0 = (y0 >= 0) && (y0 < H_); \
        const bool vy1 = (y0 + 1 >= 0) && (y0 + 1 < H_); \
        const bool vx0 = (x0 >= 0) && (x0 < W_); \
        const bool vx1 = (x0 + 1 >= 0) && (x0 + 1 < W_); \
        cw[s].x = (vy0 && vx0) ? wy0 * wx0 : 0.0f; \
        cw[s].y = (vy0 && vx1) ? wy0 * wx1 : 0.0f; \
        cw[s].z = (vy1 && vx0) ? wy1 * wx0 : 0.0f; \
        cw[s].w = (vy1 && vx1) ? wy1 * wx1 : 0.0f; \
        const int yc0 = min(max(y0, 0), H_ - 1), yc1 = min(max(y0 + 1, 0), H_ - 1); \
        const int xc0 = min(max(x0, 0), W_ - 1), xc1 = min(max(x0 + 1, 0), W_ - 1); \
        const unsigned short* pA = xb + (size_t)(yc0 * W_ + xc0) * 32; \
        const unsigned short* pB = xb + (size_t)(yc0 * W_ + xc1) * 32; \
        const unsigned short* pC = xb + (size_t)(yc1 * W_ + xc0) * 32; \
        const unsigned short* pD = xb + (size_t)(yc1 * W_ + xc1) * 32; \
        gA0[s] = *(const u32x4*)(pA);  gA1[s] = *(const u32x4*)(pA + 16); \
        gB0[s] = *(const u32x4*)(pB);  gB1[s] = *(const u32x4*)(pB + 16); \
        gC0[s] = *(const u32x4*)(pC);  gC1[s] = *(const u32x4*)(pC + 16); \
        gD0[s] = *(const u32x4*)(pD);  gD1[s] = *(const u32x4*)(pD + 16); \
    } while (0)

    PREP(0, 0);
    #pragma unroll
    for (int tap = 0; tap < 9; ++tap) {
        const int cur = tap & 1, nxt = cur ^ 1;
        if (tap < 8) PREP(tap + 1, nxt);   // issue next tap's 8 gathers
        __builtin_amdgcn_sched_barrier(0); // pin: loads stay above combine

        const float w00 = cw[cur].x, w01 = cw[cur].y;
        const float w10 = cw[cur].z, w11 = cw[cur].w;
        // PROVEN scalar-f32x2 bilinear combine + 1-op RNE bf16 pack
        #define COMB(a, bb, cc, dd) ({ \
            const f32x2 v = up2(a) * w00 + up2(bb) * w01 + up2(cc) * w10 + up2(dd) * w11; \
            cvt_pk_bf16(v.x, v.y); })
        u32x4 av0, av1;
        av0.x = COMB(gA0[cur].x, gB0[cur].x, gC0[cur].x, gD0[cur].x);
        av0.y = COMB(gA0[cur].y, gB0[cur].y, gC0[cur].y, gD0[cur].y);
        av0.z = COMB(gA0[cur].z, gB0[cur].z, gC0[cur].z, gD0[cur].z);
        av0.w = COMB(gA0[cur].w, gB0[cur].w, gC0[cur].w, gD0[cur].w);
        av1.x = COMB(gA1[cur].x, gB1[cur].x, gC1[cur].x, gD1[cur].x);
        av1.y = COMB(gA1[cur].y, gB1[cur].y, gC1[cur].y, gD1[cur].y);
        av1.z = COMB(gA1[cur].z, gB1[cur].z, gC1[cur].z, gD1[cur].z);
        av1.w = COMB(gA1[cur].w, gB1[cur].w, gC1[cur].w, gD1[cur].w);
        #undef COMB

        const short8 a0 = __builtin_bit_cast(short8, av0);
        const short8 a1 = __builtin_bit_cast(short8, av1);
        const short8 b0 = *(const short8*)(wsh + ((tap * 2 + 0) * 64 + lane) * 8);
        const short8 b1 = *(const short8*)(wsh + ((tap * 2 + 1) * 64 + lane) * 8);
        acc = __builtin_amdgcn_mfma_f32_32x32x16_bf16(a0, b0, acc, 0, 0, 0);
        acc = __builtin_amdgcn_mfma_f32_32x32x16_bf16(a1, b1, acc, 0, 0, 0);
    }
    #undef PREP

    // D: col o = n; rows = pixels pixbase + g*8 + 4*hh + i
    float* __restrict__ ob = out + (size_t)b * 32 * HW_ + (size_t)n * HW_
                           + (pixbase - b * HW_) + 4 * hh;
    #pragma unroll
    for (int g = 0; g < 4; ++g) {
        f32x4 r;
        #pragma unroll
        for (int i = 0; i < 4; ++i) r[i] = fmaxf(acc[g * 4 + i], 0.0f);
        *(f32x4*)(ob + g * 8) = r;
    }
}

extern "C" void kernel_launch(void* const* d_in, const int* in_sizes, int n_in,
                              void* d_out, int out_size, void* d_ws, size_t ws_size,
                              hipStream_t stream) {
    const float* x     = (const float*)d_in[0];
    const float* w_off = (const float*)d_in[1];
    const float* b_off = (const float*)d_in[2];
    const float* w_dcn = (const float*)d_in[3];
    float* out = (float*)d_out;

    unsigned short* xT = (unsigned short*)d_ws;   // 13.1 MB bf16 NHWC (R11 footprint)

    nhwc_bf16<<<800, 256, 0, stream>>>(x, xT);
    dcn_fused<<<1600, 256, 0, stream>>>(xT, w_off, b_off, w_dcn, out);
}

// Round 15
// 138.099 us; speedup vs baseline: 1.0555x; 1.0036x over previous
//
#include <hip/hip_runtime.h>

#define H_ 160
#define W_ 160
#define HW_ (H_ * W_)
#define NPIX (8 * HW_)   // 204800 pixels

// ============================================================================
// R25: R24 (63us, best-family) + XOR bank-swizzle on wsh units.
// R24 counters: SQ_LDS_BANK_CONFLICT 5.76M = 3600 cyc/block ~ 15% of per-CU
// cycles. Localized: staging scatter ds_write_b16 — within a wave, j fixed,
// tap varies at 1024B stride (multiple of 128B bank period) -> 64 lanes in
// ~4 banks = ~16-way serialization, twice per block, barrier-bounded.
// Fix: phys_unit = unit ^ (ts&7) (bijection within each tap-group's 64
// units; ts = tap*2+s). Writes: tap now perturbs bank bits -> ~2-way (free).
// Reads: lane reads ((ts*64+lane)^(ts&7))*8 — ts&7 is a compile-time const
// per unrolled tap; 64 lanes still cover 64 distinct contiguous 16B regions
// -> read conflict profile unchanged (conflict-free). Same involution both
// sides => value-identical kernel (pure slot permutation).
// Everything else verbatim R24: (256,4), time-shared wsh, no zero-fill,
// f16-packed offl, fences, XCD swizzle, cvt_pk packs, f32x2 combine, C-write.
// Layouts (verified m74/m101 + R9 pass): A[m=lane&31][k=(lane>>5)*8+j],
// B[n=lane&31][k=...], D: col n=lane&31, row=(reg&3)+8*(reg>>2)+4*(lane>>5).
// ============================================================================

typedef __attribute__((ext_vector_type(8)))  short  short8;   // 8 bf16
typedef __attribute__((ext_vector_type(4)))  float  f32x4;
typedef __attribute__((ext_vector_type(2)))  float  f32x2;
typedef __attribute__((ext_vector_type(16))) float  f32x16;
typedef __attribute__((ext_vector_type(4)))  unsigned u32x4;

__device__ __forceinline__ unsigned short bf16_rne(float f) {
    unsigned u = __float_as_uint(f);
    u += 0x7fffu + ((u >> 16) & 1u);
    return (unsigned short)(u >> 16);
}
// v_cvt_pk_bf16_f32: dst.lo=bf16(a), dst.hi=bf16(b); RNE (R18-verified).
__device__ __forceinline__ unsigned cvt_pk_bf16(float a, float b) {
    unsigned r;
    asm("v_cvt_pk_bf16_f32 %0, %1, %2" : "=v"(r) : "v"(a), "v"(b));
    return r;
}
__device__ __forceinline__ f32x2 up2(unsigned u) {
    f32x2 r;
    r.x = __uint_as_float(u << 16);
    r.y = __uint_as_float(u & 0xffff0000u);
    return r;
}
__device__ __forceinline__ unsigned short f16_bits(float f) {
    _Float16 h = (_Float16)f;                 // v_cvt_f16_f32 (RNE)
    return __builtin_bit_cast(unsigned short, h);
}
__device__ __forceinline__ float f16_val(unsigned short u) {
    return (float)__builtin_bit_cast(_Float16, u);   // v_cvt_f32_f16
}

// ---- x (B,32,H,W) fp32 -> xT (B,H,W,32) bf16; 16B stores (R18 verbatim) ----
__global__ __launch_bounds__(256) void nhwc_bf16(
    const float* __restrict__ x, unsigned short* __restrict__ xT)
{
    const int pix = blockIdx.x * 256 + threadIdx.x;
    const int p = pix % HW_;
    const int b = pix / HW_;
    const float* __restrict__ src = x + (size_t)b * 32 * HW_ + p;
    u32x4* __restrict__ dst = (u32x4*)(xT + (size_t)pix * 32);
    #pragma unroll
    for (int q = 0; q < 4; ++q) {
        u32x4 v;
        v.x = cvt_pk_bf16(src[(8 * q + 0) * HW_], src[(8 * q + 1) * HW_]);
        v.y = cvt_pk_bf16(src[(8 * q + 2) * HW_], src[(8 * q + 3) * HW_]);
        v.z = cvt_pk_bf16(src[(8 * q + 4) * HW_], src[(8 * q + 5) * HW_]);
        v.w = cvt_pk_bf16(src[(8 * q + 6) * HW_], src[(8 * q + 7) * HW_]);
        dst[q] = v;
    }
}

// scatter-destination for flat weight index f (f = j*288 + c*9 + tap),
// with XOR bank-swizzle: phys_unit = unit ^ (ts&7), ts = tap*2 + s.
__device__ __forceinline__ int wsh_slot(unsigned f) {
    const unsigned j   = f / 288u;
    const unsigned rem = f - j * 288u;
    const unsigned c   = rem / 9u;
    const unsigned tap = rem - c * 9u;
    const unsigned ts  = tap * 2u + (c >> 4);
    const unsigned unit = ts * 64u + j + 32u * ((c >> 3) & 1u);
    const unsigned phys = unit ^ (ts & 7u);
    return (int)(phys * 8u + (c & 7u));
}
// read-side index for logical unit (ts*64 + lane): same involution
__device__ __forceinline__ int wsh_rd(int ts, int lane) {
    return (((ts * 64 + lane) ^ (ts & 7)) * 8);
}

// ---- fused: offset conv + bilinear sampling + dcn GEMM + ReLU --------------
__global__ __launch_bounds__(256, 4) void dcn_fused(
    const unsigned short* __restrict__ xT,   // (8,160,160,32) bf16
    const float* __restrict__ w_off,         // (18, 32, 3, 3) = 5184 floats
    const float* __restrict__ b_off,         // (18,)
    const float* __restrict__ w_dcn,         // (32, 32, 3, 3) = 9216 floats
    float* __restrict__ out)                 // (8, 32, 160, 160)
{
    // ONE weight-frag buffer, time-shared: wo in stage 1, wd in stage 2.
    // NO zero-fill: garbage in lanes j>=18 only reaches unread acc cols 18-31.
    __shared__ __align__(16) unsigned short wsh[9 * 2 * 64 * 8];  // 18,432 B
    // per-wave offset transpose, packed (dy,dx) f16 per tap: [9][33] u32/wave
    __shared__ unsigned offl[4 * 9 * 33];                         //  4,752 B
    const int tid = threadIdx.x;

    // ---- stage wo: flat-coalesced loads + swizzled scatter (5184 floats) ----
    for (unsigned f = tid; f < 5184u; f += 256u)
        wsh[wsh_slot(f)] = bf16_rne(w_off[f]);
    __syncthreads();

    const int wave = tid >> 6, lane = tid & 63;
    const int n = lane & 31;          // pixel (A-row m) == out channel (D-col)
    const int hh = lane >> 5;         // k-group
    // XCD-chunked swizzle: XCD k owns batch k (200 blocks = one image = 1.6MB
    // xT -> L2-resident per XCD). Bijective since 1600 % 8 == 0.
    const int bid = (blockIdx.x & 7) * 200 + (blockIdx.x >> 3);
    const int pixbase = bid * 128 + wave * 32;
    const int pix = pixbase + n;
    const int w = pix % W_, h = (pix / W_) % H_, b = pix / HW_;
    const unsigned short* __restrict__ xb = xT + (size_t)b * HW_ * 32 + hh * 8;

    // ------- stage 1: offset conv GEMM, all 18 gathers issued up front -----
    {
        f32x16 acc = {};
        const u32x4 z4 = {0u, 0u, 0u, 0u};
        u32x4 lr[18];      // raw gathers (static indices under full unroll)
        int   va[9];       // per-tap validity
        #pragma unroll
        for (int tap = 0; tap < 9; ++tap) {
            const int yy = h - 1 + tap / 3;
            const int xx = w - 1 + tap % 3;
            va[tap] = (yy >= 0) && (yy < H_) && (xx >= 0) && (xx < W_);
            const int idx = min(max(yy, 0), H_ - 1) * W_ + min(max(xx, 0), W_ - 1);
            const unsigned short* __restrict__ px_ = xb + (size_t)idx * 32;
            lr[2 * tap]     = *(const u32x4*)(px_);
            lr[2 * tap + 1] = *(const u32x4*)(px_ + 16);
        }
        __builtin_amdgcn_sched_barrier(0);   // all 18 loads issue before use
        #pragma unroll
        for (int tap = 0; tap < 9; ++tap) {
            const u32x4 l0 = va[tap] ? lr[2 * tap]     : z4;
            const u32x4 l1 = va[tap] ? lr[2 * tap + 1] : z4;
            const short8 a0 = __builtin_bit_cast(short8, l0);
            const short8 a1 = __builtin_bit_cast(short8, l1);
            const short8 b0 = *(const short8*)(wsh + wsh_rd(tap * 2 + 0, lane));
            const short8 b1 = *(const short8*)(wsh + wsh_rd(tap * 2 + 1, lane));
            acc = __builtin_amdgcn_mfma_f32_32x32x16_bf16(a0, b0, acc, 0, 0, 0);
            acc = __builtin_amdgcn_mfma_f32_32x32x16_bf16(a1, b1, acc, 0, 0, 0);
        }
        // D-layout -> per-wave LDS transpose, f16-packed:
        // word [j>>1][prow], half (j&1): lo=dy (j even), hi=dx (j odd)
        if (n < 18) {
            const float bia = b_off[n];
            unsigned short* __restrict__ owp =
                (unsigned short*)(offl + wave * 297) + (n >> 1) * 66 + (n & 1);
            #pragma unroll
            for (int r = 0; r < 16; ++r) {
                const int prow = (r & 3) + 8 * (r >> 2) + 4 * hh;
                owp[prow * 2] = f16_bits(acc[r] + bia);
            }
        }
    }
    __syncthreads();   // stage-1 reads of wsh done everywhere; offl visible

    // ---- re-stage wd: flat-coalesced loads + swizzled scatter (9216) ----
    for (unsigned f = tid; f < 9216u; f += 256u)
        wsh[wsh_slot(f)] = bf16_rne(w_dcn[f]);
    __syncthreads();   // wd visible

    // ------ stage 2: bilinear sampling + dcn GEMM, depth-1 pipelined -------
    const unsigned* __restrict__ ow32 = offl + wave * 297;
    f32x16 acc = {};

    // double-buffered pipeline state (indices static under full unroll)
    u32x4 gA0[2], gA1[2], gB0[2], gB1[2], gC0[2], gC1[2], gD0[2], gD1[2];
    f32x4 cw[2];   // {w00, w01, w10, w11}

    #define PREP(t, s) do { \
        const unsigned dyx = ow32[(t) * 33 + n]; \
        const float dy = f16_val((unsigned short)(dyx & 0xffffu)); \
        const float dx = f16_val((unsigned short)(dyx >> 16)); \
        const float py = (float)(h - 1 + (t) / 3) + dy; \
        const float px = (float)(w - 1 + (t) % 3) + dx; \
        const float fy0 = floorf(py), fx0 = floorf(px); \
        const float wy1 = py - fy0, wx1 = px - fx0; \
        const float wy0 = 1.0f - wy1, wx0 = 1.0f - wx1; \
        const int y0 = (int)fy0, x0 = (int)fx0; \
        const bool vy0 = (y0 >= 0) && (y0 < H_); \
        const bool vy1 = (y0 + 1 >= 0) && (y0 + 1 < H_); \
        const bool vx0 = (x0 >= 0) && (x0 < W_); \
        const bool vx1 = (x0 + 1 >= 0) && (x0 + 1 < W_); \
        cw[s].x = (vy0 && vx0) ? wy0 * wx0 : 0.0f; \
        cw[s].y = (vy0 && vx1) ? wy0 * wx1 : 0.0f; \
        cw[s].z = (vy1 && vx0) ? wy1 * wx0 : 0.0f; \
        cw[s].w = (vy1 && vx1) ? wy1 * wx1 : 0.0f; \
        const int yc0 = min(max(y0, 0), H_ - 1), yc1 = min(max(y0 + 1, 0), H_ - 1); \
        const int xc0 = min(max(x0, 0), W_ - 1), xc1 = min(max(x0 + 1, 0), W_ - 1); \
        const unsigned short* pA = xb + (size_t)(yc0 * W_ + xc0) * 32; \
        const unsigned short* pB = xb + (size_t)(yc0 * W_ + xc1) * 32; \
        const unsigned short* pC = xb + (size_t)(yc1 * W_ + xc0) * 32; \
        const unsigned short* pD = xb + (size_t)(yc1 * W_ + xc1) * 32; \
        gA0[s] = *(const u32x4*)(pA);  gA1[s] = *(const u32x4*)(pA + 16); \
        gB0[s] = *(const u32x4*)(pB);  gB1[s] = *(const u32x4*)(pB + 16); \
        gC0[s] = *(const u32x4*)(pC);  gC1[s] = *(const u32x4*)(pC + 16); \
        gD0[s] = *(const u32x4*)(pD);  gD1[s] = *(const u32x4*)(pD + 16); \
    } while (0)

    PREP(0, 0);
    #pragma unroll
    for (int tap = 0; tap < 9; ++tap) {
        const int cur = tap & 1, nxt = cur ^ 1;
        if (tap < 8) PREP(tap + 1, nxt);   // issue next tap's 8 gathers
        __builtin_amdgcn_sched_barrier(0); // pin: loads stay above combine

        const float w00 = cw[cur].x, w01 = cw[cur].y;
        const float w10 = cw[cur].z, w11 = cw[cur].w;
        // PROVEN scalar-f32x2 bilinear combine + 1-op RNE bf16 pack
        #define COMB(a, bb, cc, dd) ({ \
            const f32x2 v = up2(a) * w00 + up2(bb) * w01 + up2(cc) * w10 + up2(dd) * w11; \
            cvt_pk_bf16(v.x, v.y); })
        u32x4 av0, av1;
        av0.x = COMB(gA0[cur].x, gB0[cur].x, gC0[cur].x, gD0[cur].x);
        av0.y = COMB(gA0[cur].y, gB0[cur].y, gC0[cur].y, gD0[cur].y);
        av0.z = COMB(gA0[cur].z, gB0[cur].z, gC0[cur].z, gD0[cur].z);
        av0.w = COMB(gA0[cur].w, gB0[cur].w, gC0[cur].w, gD0[cur].w);
        av1.x = COMB(gA1[cur].x, gB1[cur].x, gC1[cur].x, gD1[cur].x);
        av1.y = COMB(gA1[cur].y, gB1[cur].y, gC1[cur].y, gD1[cur].y);
        av1.z = COMB(gA1[cur].z, gB1[cur].z, gC1[cur].z, gD1[cur].z);
        av1.w = COMB(gA1[cur].w, gB1[cur].w, gC1[cur].w, gD1[cur].w);
        #undef COMB

        const short8 a0 = __builtin_bit_cast(short8, av0);
        const short8 a1 = __builtin_bit_cast(short8, av1);
        const short8 b0 = *(const short8*)(wsh + wsh_rd(tap * 2 + 0, lane));
        const short8 b1 = *(const short8*)(wsh + wsh_rd(tap * 2 + 1, lane));
        acc = __builtin_amdgcn_mfma_f32_32x32x16_bf16(a0, b0, acc, 0, 0, 0);
        acc = __builtin_amdgcn_mfma_f32_32x32x16_bf16(a1, b1, acc, 0, 0, 0);
    }
    #undef PREP

    // D: col o = n; rows = pixels pixbase + g*8 + 4*hh + i
    float* __restrict__ ob = out + (size_t)b * 32 * HW_ + (size_t)n * HW_
                           + (pixbase - b * HW_) + 4 * hh;
    #pragma unroll
    for (int g = 0; g < 4; ++g) {
        f32x4 r;
        #pragma unroll
        for (int i = 0; i < 4; ++i) r[i] = fmaxf(acc[g * 4 + i], 0.0f);
        *(f32x4*)(ob + g * 8) = r;
    }
}

extern "C" void kernel_launch(void* const* d_in, const int* in_sizes, int n_in,
                              void* d_out, int out_size, void* d_ws, size_t ws_size,
                              hipStream_t stream) {
    const float* x     = (const float*)d_in[0];
    const float* w_off = (const float*)d_in[1];
    const float* b_off = (const float*)d_in[2];
    const float* w_dcn = (const float*)d_in[3];
    float* out = (float*)d_out;

    unsigned short* xT = (unsigned short*)d_ws;   // 13.1 MB bf16 NHWC (R11 footprint)

    nhwc_bf16<<<800, 256, 0, stream>>>(x, xT);
    dcn_fused<<<1600, 256, 0, stream>>>(xT, w_off, b_off, w_dcn, out);
}